// Round 1
// baseline (4837.909 us; speedup 1.0000x reference)
//
#include <hip/hip_runtime.h>
#include <math.h>

// VectorQuantization on MI355X (gfx950).
// x: [B=16, D=512, N=8192] fp32, embed: [K=2048, D=512] fp32.
// out = quantize [B,D,N] fp32 (67108864 floats) ++ embed_ind [B,N] as fp32 (131072).
//
// Round 0: fp32 register-tiled baseline. Compute floor 2.75e11 FLOP / 157 TF
// ~= 1.75 ms; memory floor ~81 us. Expect ~2.5 ms, VALUBusy-bound, MfmaUtil 0.

constexpr int B = 16, D = 512, N = 8192, K = 2048;
constexpr int TN = 64;   // n rows per block
constexpr int TK = 64;   // codes per k-tile
constexpr int TD = 64;   // d chunk
constexpr int TDp = TD + 4;  // pad keeps float4 alignment, 2-way conflicts (free)

// ---- kernel 0: e2[k] = sum_d embed[k][d]^2 (one wave per k, tree reduce) ----
__global__ __launch_bounds__(256) void e2_kernel(const float* __restrict__ embed,
                                                 float* __restrict__ e2) {
    int k = blockIdx.x * 4 + (threadIdx.x >> 6);
    int lane = threadIdx.x & 63;
    const float* row = embed + (size_t)k * D;
    float s = 0.f;
    #pragma unroll
    for (int d = 0; d < D; d += 64) {  // 8 strided partials per lane
        float v = row[d + lane];
        s = fmaf(v, v, s);
    }
    #pragma unroll
    for (int off = 32; off; off >>= 1) s += __shfl_down(s, off, 64);
    if (lane == 0) e2[k] = s;
}

// ---- kernel 1: argmax of (2*x.e - |e|^2) per row + fused gather/write ----
__global__ __launch_bounds__(256) void vq_kernel(const float* __restrict__ x,
                                                 const float* __restrict__ embed,
                                                 const float* __restrict__ e2g,
                                                 float* __restrict__ out) {
    __shared__ float As[TD][TN];    // x tile, [d][n] — direct copy (x is d-major)
    __shared__ float Es[TK][TDp];   // embed tile, [k][d], padded
    __shared__ float redV[16][TN];
    __shared__ int   redI[16][TN];
    __shared__ int   finalIdx[TN];

    const int t  = threadIdx.x;
    const int tr = t & 15;        // row group: rows tr*4 .. tr*4+3 (lane-consecutive)
    const int tc = t >> 4;        // col group: codes tc*4 .. tc*4+3 within tile
    const int b  = blockIdx.y;
    const int n0 = blockIdx.x * TN;

    const float* xb = x + (size_t)b * D * N + n0;

    const int ld_row = t >> 4;          // 0..15
    const int ld_col = (t & 15) * 4;    // 0..60, float4

    float bestV[4];
    int   bestI[4];
    #pragma unroll
    for (int i = 0; i < 4; ++i) { bestV[i] = -3.402823466e38f; bestI[i] = 0; }

    for (int kt = 0; kt < K / TK; ++kt) {
        float acc[4][4] = {};
        for (int dt = 0; dt < D / TD; ++dt) {
            // stage x tile: As[dd][nn] = x[b][dt*64+dd][n0+nn] (coalesced float4)
            #pragma unroll
            for (int p = 0; p < 4; ++p) {
                int dd = p * 16 + ld_row;
                *(float4*)&As[dd][ld_col] =
                    *(const float4*)&xb[(size_t)(dt * TD + dd) * N + ld_col];
            }
            // stage embed tile: Es[kk][dd] = embed[kt*64+kk][dt*64+dd]
            #pragma unroll
            for (int p = 0; p < 4; ++p) {
                int kk = p * 16 + ld_row;
                *(float4*)&Es[kk][ld_col] =
                    *(const float4*)&embed[(size_t)(kt * TK + kk) * D + dt * TD + ld_col];
            }
            __syncthreads();

            #pragma unroll 2
            for (int dq = 0; dq < TD; dq += 4) {
                float av[4][4], ev[4][4];   // av[q][i]: depth q, row i; ev[j][q]
                #pragma unroll
                for (int q = 0; q < 4; ++q) {
                    float4 t4 = *(const float4*)&As[dq + q][tr * 4];
                    av[q][0] = t4.x; av[q][1] = t4.y; av[q][2] = t4.z; av[q][3] = t4.w;
                }
                #pragma unroll
                for (int j = 0; j < 4; ++j) {
                    float4 t4 = *(const float4*)&Es[tc * 4 + j][dq];
                    ev[j][0] = t4.x; ev[j][1] = t4.y; ev[j][2] = t4.z; ev[j][3] = t4.w;
                }
                #pragma unroll
                for (int i = 0; i < 4; ++i)
                    #pragma unroll
                    for (int j = 0; j < 4; ++j) {
                        float s = acc[i][j];
                        #pragma unroll
                        for (int q = 0; q < 4; ++q) s = fmaf(av[q][i], ev[j][q], s);
                        acc[i][j] = s;
                    }
            }
            __syncthreads();
        }
        // fold tile into running best (ascending k per thread -> strict > keeps
        // first-max, matching numpy argmax)
        #pragma unroll
        for (int j = 0; j < 4; ++j) {
            int k = kt * TK + tc * 4 + j;
            float ek = e2g[k];
            #pragma unroll
            for (int i = 0; i < 4; ++i) {
                float s = 2.0f * acc[i][j] - ek;
                if (s > bestV[i]) { bestV[i] = s; bestI[i] = k; }
            }
        }
    }

    // cross-thread reduction over the 16 col-groups, lower-index tie-break
    #pragma unroll
    for (int i = 0; i < 4; ++i) {
        redV[tc][tr * 4 + i] = bestV[i];
        redI[tc][tr * 4 + i] = bestI[i];
    }
    __syncthreads();
    if (t < TN) {
        float bv = redV[0][t];
        int   bi = redI[0][t];
        #pragma unroll
        for (int c = 1; c < 16; ++c) {
            float v = redV[c][t];
            int   idx = redI[c][t];
            if (v > bv || (v == bv && idx < bi)) { bv = v; bi = idx; }
        }
        finalIdx[t] = bi;
        // index output, [B,N], written as float
        out[(size_t)B * D * N + (size_t)b * N + n0 + t] = (float)bi;
    }
    __syncthreads();

    // fused gather: out[b][d][n0+nn] = embed[finalIdx[nn]][d]
    // lanes consecutive in nn -> coalesced 256B stores; reads are L2-resident
    // gathers (embed = 4 MB fits per-XCD L2).
    {
        int nn = t & 63;
        int code = finalIdx[nn];
        const float* erow = embed + (size_t)code * D;
        float* ob = out + (size_t)b * D * N + n0 + nn;
        for (int d = (t >> 6); d < D; d += 4) {
            ob[(size_t)d * N] = erow[d];
        }
    }
}

extern "C" void kernel_launch(void* const* d_in, const int* in_sizes, int n_in,
                              void* d_out, int out_size, void* d_ws, size_t ws_size,
                              hipStream_t stream) {
    const float* x     = (const float*)d_in[0];
    const float* embed = (const float*)d_in[1];
    float* out = (float*)d_out;
    float* e2  = (float*)d_ws;   // 2048 floats

    e2_kernel<<<dim3(K / 4), 256, 0, stream>>>(embed, e2);
    vq_kernel<<<dim3(N / TN, B), 256, 0, stream>>>(x, embed, e2, out);
}

// Round 2
// 2112.943 us; speedup vs baseline: 2.2897x; 2.2897x over previous
//
#include <hip/hip_runtime.h>
#include <math.h>
#include <stdint.h>

// VectorQuantization, round 2: split-bf16 MFMA (3-term) GEMM + fused argmax.
// x: [B=16, D=512, N=8192] fp32, embed: [K=2048, D=512] fp32.
// out = quantize [B,D,N] fp32 ++ embed_ind [B,N] as fp32.
//
// dot(x,e) ~= xh.eh + xh.el + xl.eh  (bf16 RNE splits, fp32 MFMA acc)
// MFMA floor: 3*2.75e11 FLOP / 2.5 PF = 330 us. Target 600-1000 us.

constexpr int B = 16, D = 512, N = 8192, K = 2048;

typedef __attribute__((ext_vector_type(8)))  short   short8;    // bf16x8 frag
typedef __attribute__((ext_vector_type(16))) float   floatx16;  // 32x32 acc

typedef const __attribute__((address_space(1))) uint32_t* gas1_t;
typedef __attribute__((address_space(3)))       uint32_t* las3_t;

__device__ __forceinline__ void async_ld16(const float* g, float* lds) {
  // 16B per lane, LDS dest = wave-uniform base + lane*16
  __builtin_amdgcn_global_load_lds((gas1_t)g, (las3_t)lds, 16, 0, 0);
}

__device__ __forceinline__ uint32_t rne_hi(float a) {
  uint32_t u = __float_as_uint(a);
  return (u + 0x7fffu + ((u >> 16) & 1u)) & 0xffff0000u;
}

// split pair (a,b) -> hi = packed(bf16(a), bf16(b)), lo = packed residuals
__device__ __forceinline__ void split2(float a, float b, uint32_t& hi, uint32_t& lo) {
  uint32_t ha = rne_hi(a), hb = rne_hi(b);
  float ra = a - __uint_as_float(ha);
  float rb = b - __uint_as_float(hb);
  hi = (ha >> 16) | hb;
  uint32_t la = rne_hi(ra), lb = rne_hi(rb);
  lo = (la >> 16) | lb;
}

// ---- kernel 0: e2[k] = sum_d embed[k][d]^2 ----
__global__ __launch_bounds__(256) void e2_kernel(const float* __restrict__ embed,
                                                 float* __restrict__ e2) {
  int k = blockIdx.x * 4 + (threadIdx.x >> 6);
  int lane = threadIdx.x & 63;
  const float* row = embed + (size_t)k * D;
  float s = 0.f;
  #pragma unroll
  for (int d = 0; d < D; d += 64) {
    float v = row[d + lane];
    s = fmaf(v, v, s);
  }
  #pragma unroll
  for (int off = 32; off; off >>= 1) s += __shfl_down(s, off, 64);
  if (lane == 0) e2[k] = s;
}

// ---- main kernel: 128 n-rows x all 2048 codes, MFMA 32x32x16 ----
__global__ __launch_bounds__(256, 2) void vq_mfma(const float* __restrict__ x,
                                                  const float* __restrict__ embed,
                                                  const float* __restrict__ e2g,
                                                  float* __restrict__ out) {
  // LDS: 64 KB total
  __shared__ float    Xraw[64 * 128];    // [d][n] fp32, unpadded (32 KB)
  __shared__ uint16_t Ehi[128 * 64];     // [c][d] bf16 hi, XOR-swizzled (16 KB)
  __shared__ uint16_t Elo[128 * 64];     // [c][d] bf16 lo (16 KB)

  const int t    = threadIdx.x;
  const int lane = t & 63;
  const int wid  = t >> 6;
  const int wm   = wid & 1;    // code-dim wave coord
  const int wn   = wid >> 1;   // n-dim wave coord
  const int l31  = lane & 31;
  const int lh   = lane >> 5;  // half-wave

  const int b  = blockIdx.y;
  const int n0 = blockIdx.x * 128;
  const float* xb = x + (size_t)b * D * N + n0;

  float bestV[2] = {-3.402823466e38f, -3.402823466e38f};
  int   bestI[2] = {0, 0};

  for (int kt = 0; kt < K / 128; ++kt) {
    floatx16 acc[2][2];
    #pragma unroll
    for (int mt = 0; mt < 2; ++mt)
      #pragma unroll
      for (int nt = 0; nt < 2; ++nt)
        #pragma unroll
        for (int i = 0; i < 16; ++i) acc[mt][nt][i] = 0.f;

    for (int dt = 0; dt < D / 64; ++dt) {
      // ---- stage X: async fp32, wave wid loads d-rows [wid*16 .. +15] ----
      {
        // one instr = 1 KB = 2 d-rows (lanes 0..31 row d, 32..63 row d+1)
        const float* g0 = xb + (size_t)(dt * 64 + wid * 16 + lh) * N + l31 * 4;
        #pragma unroll
        for (int i = 0; i < 8; ++i) {
          async_ld16(g0 + (size_t)(i * 2) * N, &Xraw[(wid * 16 + i * 2) * 128]);
        }
      }
      // ---- stage E: manual fp32 -> bf16 hi/lo, swizzled runs of 8 ----
      {
        const float* eb = embed + (size_t)(kt * 128) * D + dt * 64;
        const int f4 = t & 15;            // 16 float4 per row = 64 d
        const int cr = t >> 4;            // 16 codes per pass
        #pragma unroll
        for (int p = 0; p < 8; ++p) {
          int c = p * 16 + cr;
          const float4 v = *(const float4*)(eb + (size_t)c * D + f4 * 4);
          uint32_t h0, l0, h1, l1;
          split2(v.x, v.y, h0, l0);
          split2(v.z, v.w, h1, l1);
          int run = f4 >> 1, half = f4 & 1;
          int off = ((run ^ (c & 7)) * 8 + half * 4);   // element offset in row
          *(uint2*)&Ehi[c * 64 + off] = make_uint2(h0, h1);
          *(uint2*)&Elo[c * 64 + off] = make_uint2(l0, l1);
        }
      }
      __syncthreads();   // compiler drains vmcnt(0) for global_load_lds here

      #pragma unroll
      for (int ks = 0; ks < 4; ++ks) {
        // A fragments (embed): m = l31, k = ks*16 + lh*8 + j
        short8 ahi[2], alo[2];
        #pragma unroll
        for (int mt = 0; mt < 2; ++mt) {
          int c = wm * 64 + mt * 32 + l31;
          int run = ks * 2 + lh;
          int off = (run ^ (c & 7)) * 8;
          ahi[mt] = *(const short8*)&Ehi[c * 64 + off];
          alo[mt] = *(const short8*)&Elo[c * 64 + off];
        }
        // B fragments (x): read raw fp32, split in-register
        short8 bhi[2], blo[2];
        #pragma unroll
        for (int nt = 0; nt < 2; ++nt) {
          int n = wn * 64 + nt * 32 + l31;
          int kb = ks * 16 + lh * 8;
          float r0 = Xraw[(kb + 0) * 128 + n];
          float r1 = Xraw[(kb + 1) * 128 + n];
          float r2 = Xraw[(kb + 2) * 128 + n];
          float r3 = Xraw[(kb + 3) * 128 + n];
          float r4 = Xraw[(kb + 4) * 128 + n];
          float r5 = Xraw[(kb + 5) * 128 + n];
          float r6 = Xraw[(kb + 6) * 128 + n];
          float r7 = Xraw[(kb + 7) * 128 + n];
          union { short8 s; uint32_t u[4]; } Bh, Bl;
          split2(r0, r1, Bh.u[0], Bl.u[0]);
          split2(r2, r3, Bh.u[1], Bl.u[1]);
          split2(r4, r5, Bh.u[2], Bl.u[2]);
          split2(r6, r7, Bh.u[3], Bl.u[3]);
          bhi[nt] = Bh.s; blo[nt] = Bl.s;
        }
        #pragma unroll
        for (int mt = 0; mt < 2; ++mt)
          #pragma unroll
          for (int nt = 0; nt < 2; ++nt) {
            acc[mt][nt] = __builtin_amdgcn_mfma_f32_32x32x16_bf16(
                ahi[mt], bhi[nt], acc[mt][nt], 0, 0, 0);
            acc[mt][nt] = __builtin_amdgcn_mfma_f32_32x32x16_bf16(
                ahi[mt], blo[nt], acc[mt][nt], 0, 0, 0);
            acc[mt][nt] = __builtin_amdgcn_mfma_f32_32x32x16_bf16(
                alo[mt], bhi[nt], acc[mt][nt], 0, 0, 0);
          }
      }
      __syncthreads();
    } // dt

    // ---- fold into running argmax (ascending code order -> first-max) ----
    #pragma unroll
    for (int mt = 0; mt < 2; ++mt) {
      #pragma unroll
      for (int r = 0; r < 16; ++r) {
        int row  = (r & 3) + 8 * (r >> 2) + 4 * lh;
        int code = kt * 128 + wm * 64 + mt * 32 + row;
        float ek = e2g[code];
        #pragma unroll
        for (int nt = 0; nt < 2; ++nt) {
          float s = 2.0f * acc[mt][nt][r] - ek;
          if (s > bestV[nt]) { bestV[nt] = s; bestI[nt] = code; }
        }
      }
    }
  } // kt

  // ---- cross-wave reduction (alias Xraw region) ----
  __syncthreads();
  float* redV = Xraw;                       // [128][4]
  int*   redI = (int*)(Xraw + 512);         // [128][4]
  int*   fIdx = (int*)(Xraw + 1024);        // [128]

  #pragma unroll
  for (int nt = 0; nt < 2; ++nt) {
    int n = wn * 64 + nt * 32 + l31;
    int slot = lh + 2 * wm;
    redV[n * 4 + slot] = bestV[nt];
    redI[n * 4 + slot] = bestI[nt];
  }
  __syncthreads();
  if (t < 128) {
    float bv = redV[t * 4]; int bi = redI[t * 4];
    #pragma unroll
    for (int s = 1; s < 4; ++s) {
      float v = redV[t * 4 + s]; int ii = redI[t * 4 + s];
      if (v > bv || (v == bv && ii < bi)) { bv = v; bi = ii; }
    }
    fIdx[t] = bi;
    out[(size_t)B * D * N + (size_t)b * N + n0 + t] = (float)bi;
  }
  __syncthreads();

  // ---- fused gather: out[b][d][n0+n] = embed[fIdx[n]][d] ----
  {
    int n = t & 127;
    int code = fIdx[n];
    const float* erow = embed + (size_t)code * D;
    float* ob = out + (size_t)b * D * N + n0 + n;
    for (int d = (t >> 7); d < D; d += 2) {
      ob[(size_t)d * N] = erow[d];
    }
  }
}

extern "C" void kernel_launch(void* const* d_in, const int* in_sizes, int n_in,
                              void* d_out, int out_size, void* d_ws, size_t ws_size,
                              hipStream_t stream) {
  const float* x     = (const float*)d_in[0];
  const float* embed = (const float*)d_in[1];
  float* out = (float*)d_out;
  float* e2  = (float*)d_ws;   // 2048 floats

  e2_kernel<<<dim3(K / 4), 256, 0, stream>>>(embed, e2);
  vq_mfma<<<dim3(N / 128, B), 256, 0, stream>>>(x, embed, e2, out);
}